// Round 12
// baseline (599.791 us; speedup 1.0000x reference)
//
#include <hip/hip_runtime.h>
#include <math.h>
#include <stdint.h>

// MultiResEncoding: Instant-NGP 2D multires hash grid. N=2^21, 16 levels,
// F=2, table 2^19 x float2. Level 0 dense 16x16; levels 1..15 hashed.
//
// History: R5 level->XCD split. R7 x-pair merge (PRIME[0]==1: even-ix
//   corners = one 16-B pair). R8: nt LOADS = L2 no-allocate on gfx950 --
//   never nt-load data you want cached. R11/R12: spatial binning (128x128)
//   -> sorted gathers 272->178 us (cost ~ unique lines/wave, CONFIRMED).
// R13: FUSED sorted kernel (wave j = levels 4j..4j+3): sliding hash window
//   keeps even saturated levels L2-resident (FETCH 101 MB). 588 us. VALU
//   ~50%: mre_all now half VALU- half latency-bound; machinery ~143 us.
// R14 (this round): kill machinery traffic. (a) k_init zeroes ONLY cnt
//   (64 KB, was 50 MB of sentinel records); mre_all derives validity from
//   pos < cnt[bin] (bin-uniform broadcast read; garbage slots are gated and
//   memory-safe: clamps+mask bound all indices, invalid lanes use -1 coords
//   -> merged (0,0) lines). (b) scatter coord reads nt (stream-once here).

#define TMASK  ((1u << 19) - 1)
#define PRIME2 2654435761u
#define NBIN   16384u          // 128 x 128 spatial bins
#define CAP    192u            // slots per bin = 3 blocks of 64
#define INVOG  0xFFFFFFFFu

typedef float vfloat4 __attribute__((ext_vector_type(4)));
typedef float vfloat2 __attribute__((ext_vector_type(2)));

// Divergent merged gather (R7, proven): if h1 in {h0, h0^1} (even-ix0 pair
// or clamped edge), one 16-B load covers both entries; else two 8-B loads.
__device__ __forceinline__ void pair_gather(const char* tp, unsigned h0,
                                            unsigned h1, float2& a, float2& b)
{
    if (((h0 ^ h1) | 1u) == 1u) {
        vfloat4 q = *(const vfloat4*)(tp + ((h0 & ~1u) << 3));
        a.x = (h0 & 1u) ? q.z : q.x;  a.y = (h0 & 1u) ? q.w : q.y;
        b.x = (h1 & 1u) ? q.z : q.x;  b.y = (h1 & 1u) ? q.w : q.y;
    } else {
        a = *(const float2*)(tp + ((size_t)h0 << 3));
        b = *(const float2*)(tp + ((size_t)h1 << 3));
    }
}

__device__ __forceinline__ unsigned bin_of(float x, float y)
{
    int bx = (int)(x * 128.0f); bx = bx < 0 ? 0 : (bx > 127 ? 127 : bx);
    int by = (int)(y * 128.0f); by = by < 0 ? 0 : (by > 127 ? 127 : by);
    return (unsigned)by * 128u + (unsigned)bx;
}

// ---------------- init: counters only (64 KB, not 50 MB) -----------------
__global__ void k_init(unsigned* __restrict__ cnt)
{
    unsigned i = blockIdx.x * 256u + threadIdx.x;
    if (i <= NBIN) cnt[i] = 0u;                    // bins + ocnt at [NBIN]
}

// ---------------- scatter: one atomic + ONE 16-B store per point ---------
__global__ void k_scatter(const float* __restrict__ cx, const float* __restrict__ cy,
                          unsigned* __restrict__ cnt, vfloat4* __restrict__ slots,
                          float* __restrict__ ox, float* __restrict__ oy,
                          unsigned* __restrict__ oidx, unsigned N)
{
    unsigned i = blockIdx.x * 256u + threadIdx.x;
    if (i >= N) return;
    float x = __builtin_nontemporal_load(cx + i);  // stream-once in this path
    float y = __builtin_nontemporal_load(cy + i);
    unsigned b = bin_of(x, y);
    unsigned pos = atomicAdd(&cnt[b], 1u);
    if (pos < CAP) {
        vfloat4 rec = { x, y, __uint_as_float(i), 0.0f };
        slots[b * CAP + pos] = rec;
    } else {                                       // statistically ~never
        unsigned op = atomicAdd(&cnt[NBIN], 1u);   // capacity N: always fits
        ox[op] = x; oy[op] = y; oidx[op] = i;
    }
}

// ---------------- fused main kernel: all 16 levels, sorted ---------------
// 64 sorted slots/block, 3 blocks/bin; wave j handles levels {4j..4j+3}.
__global__ __launch_bounds__(256) void mre_all(
    const vfloat4* __restrict__ slots, const unsigned* __restrict__ cnt,
    const float2* __restrict__ dense, const float2* __restrict__ hasht,
    float4* __restrict__ out, uint4 wa, uint4 wb)
{
    __shared__ float2 sdense[256];                 // 16x16 level-0 grid, 2 KB
    __shared__ __align__(16) float sout[64 * 36];  // 64 pts x 32 feats, +4 pad
    __shared__ unsigned sorig[64];
    sdense[threadIdx.x] = dense[threadIdx.x];

    unsigned j  = threadIdx.x >> 6;                // wave = level group
    unsigned nl = threadIdx.x & 63u;               // slot within block
    unsigned bid = blockIdx.x;
    unsigned bin = bid / 3u;                       // 3 blocks per bin
    unsigned pos = (bid - bin * 3u) * 64u + nl;    // slot index within bin
    unsigned bcnt = cnt[bin];                      // bin-uniform broadcast
    bool valid = (pos < bcnt);                     // (bcnt may exceed CAP)

    unsigned slot = bin * CAP + pos;
    vfloat4 rec = slots[slot];                     // coalesced 16 B (may be
    float x = valid ? rec.x : -1.0f;               //  garbage if !valid --
    float y = valid ? rec.y : -1.0f;               //  gated, memory-safe)
    if (j == 0u) sorig[nl] = valid ? __float_as_uint(rec.z) : INVOG;
    __syncthreads();

    if (__ballot(valid) != 0ull) {
        // levels 4j..4j+3 live in words 2j, 2j+1 (wave-uniform selects)
        unsigned w0 = j == 0u ? wa.x : j == 1u ? wa.z : j == 2u ? wb.x : wb.z;
        unsigned w1 = j == 0u ? wa.y : j == 1u ? wa.w : j == 2u ? wb.y : wb.w;
        int rm1[4] = { (int)(w0 & 0xffffu), (int)(w0 >> 16),
                       (int)(w1 & 0xffffu), (int)(w1 >> 16) };

        unsigned h00[4], h01[4], h10[4], h11[4];
        unsigned tbo[4];
        float wx[4], wy[4];
        unsigned d00 = 0, d01 = 0, d10 = 0, d11 = 0;

        #pragma unroll
        for (int k = 0; k < 4; ++k) {
            int r = rm1[k];
            float rf = (float)r;
            float fx = x * rf, fy = y * rf;
            float x0f = floorf(fx), y0f = floorf(fy);
            wx[k] = fx - x0f;  wy[k] = fy - y0f;
            int ix0 = (int)x0f; ix0 = ix0 < 0 ? 0 : (ix0 > r ? r : ix0);
            int iy0 = (int)y0f; iy0 = iy0 < 0 ? 0 : (iy0 > r ? r : iy0);
            int ix1 = ix0 + 1 > r ? r : ix0 + 1;
            int iy1 = iy0 + 1 > r ? r : iy0 + 1;
            if (k == 0) { d00 = ix0 * 16 + iy0; d01 = ix0 * 16 + iy1;
                          d10 = ix1 * 16 + iy0; d11 = ix1 * 16 + iy1; }
            unsigned lvl = j * 4u + (unsigned)k;   // level of this slot
            unsigned ti = lvl == 0u ? 0u : lvl - 1u;
            tbo[k] = ti << 22;                     // ti * 2^19 * 8 B
            unsigned hy0 = (unsigned)iy0 * PRIME2;
            unsigned hy1 = (unsigned)iy1 * PRIME2;
            h00[k] = ((unsigned)ix0 ^ hy0) & TMASK;
            h01[k] = ((unsigned)ix0 ^ hy1) & TMASK;
            h10[k] = ((unsigned)ix1 ^ hy0) & TMASK;
            h11[k] = ((unsigned)ix1 ^ hy1) & TMASK;
        }

        const char* hb = (const char*)hasht;
        float2 f00[4], f01[4], f10[4], f11[4];
        #pragma unroll
        for (int k = 1; k < 4; ++k) {              // unconditional: issue first
            const char* tp = hb + tbo[k];
            pair_gather(tp, h00[k], h10[k], f00[k], f10[k]);
            pair_gather(tp, h01[k], h11[k], f01[k], f11[k]);
        }
        if (j == 0u) {                             // whole wave 0: LDS dense
            f00[0] = sdense[d00]; f01[0] = sdense[d01];
            f10[0] = sdense[d10]; f11[0] = sdense[d11];
        } else {
            const char* tp = hb + tbo[0];
            pair_gather(tp, h00[0], h10[0], f00[0], f10[0]);
            pair_gather(tp, h01[0], h11[0], f01[0], f11[0]);
        }

        // bilerp -> contiguous quadrant floats [8j..8j+7] of this point's row
        float* so = &sout[nl * 36u + 8u * j];
        #pragma unroll
        for (int k = 0; k < 4; ++k) {
            float omx = 1.0f - wx[k], omy = 1.0f - wy[k];
            float w00 = omx * omy, w01 = omx * wy[k];
            float w10 = wx[k] * omy, w11 = wx[k] * wy[k];
            vfloat2 a;
            a.x = f00[k].x * w00 + f01[k].x * w01 + f10[k].x * w10 + f11[k].x * w11;
            a.y = f00[k].y * w00 + f01[k].y * w01 + f10[k].y * w10 + f11[k].y * w11;
            *(vfloat2*)&so[2u * (unsigned)k] = a;
        }
    }
    __syncthreads();

    // store: 8 lanes per point -> full 128-B line at out[orig], two passes
    unsigned c  = threadIdx.x & 7u;
    unsigned q0 = threadIdx.x >> 3;                // 0..31
    #pragma unroll
    for (int p = 0; p < 2; ++p) {
        unsigned q = q0 + 32u * p;
        unsigned oo = sorig[q];
        if (oo != INVOG) {
            vfloat4 v = *(const vfloat4*)&sout[q * 36u + c * 4u];
            __builtin_nontemporal_store(v, (vfloat4*)(out + (size_t)oo * 8u + c));
        }
    }
}

// ---------------- overflow: all 16 levels direct (exact same FP ops) -----
__global__ void k_overflow(const float* __restrict__ ox, const float* __restrict__ oy,
                           const unsigned* __restrict__ oidx,
                           const unsigned* __restrict__ cnt,
                           const float2* __restrict__ dense,
                           const float2* __restrict__ hasht,
                           float4* __restrict__ out, uint4 wa, uint4 wb)
{
    unsigned ocnt = cnt[NBIN];
    unsigned pwv[8] = { wa.x, wa.y, wa.z, wa.w, wb.x, wb.y, wb.z, wb.w };
    const char* hb = (const char*)hasht;
    for (unsigned i = blockIdx.x * 256u + threadIdx.x; i < ocnt;
         i += gridDim.x * 256u) {
        float x = ox[i], y = oy[i];
        float f[32];
        #pragma unroll
        for (int l = 0; l < 16; ++l) {
            int r = (int)((pwv[l >> 1] >> ((l & 1) << 4)) & 0xffffu);
            float rf = (float)r;
            float fx = x * rf, fy = y * rf;
            float x0f = floorf(fx), y0f = floorf(fy);
            float wx = fx - x0f, wy = fy - y0f;
            int ix0 = (int)x0f; ix0 = ix0 < 0 ? 0 : (ix0 > r ? r : ix0);
            int iy0 = (int)y0f; iy0 = iy0 < 0 ? 0 : (iy0 > r ? r : iy0);
            int ix1 = ix0 + 1 > r ? r : ix0 + 1;
            int iy1 = iy0 + 1 > r ? r : iy0 + 1;
            float2 f00, f01, f10, f11;
            if (l == 0) {
                f00 = dense[ix0 * 16 + iy0]; f01 = dense[ix0 * 16 + iy1];
                f10 = dense[ix1 * 16 + iy0]; f11 = dense[ix1 * 16 + iy1];
            } else {
                const char* tp = hb + ((size_t)(l - 1) << 22);
                unsigned hy0 = (unsigned)iy0 * PRIME2;
                unsigned hy1 = (unsigned)iy1 * PRIME2;
                f00 = *(const float2*)(tp + ((size_t)(((unsigned)ix0 ^ hy0) & TMASK) << 3));
                f01 = *(const float2*)(tp + ((size_t)(((unsigned)ix0 ^ hy1) & TMASK) << 3));
                f10 = *(const float2*)(tp + ((size_t)(((unsigned)ix1 ^ hy0) & TMASK) << 3));
                f11 = *(const float2*)(tp + ((size_t)(((unsigned)ix1 ^ hy1) & TMASK) << 3));
            }
            float omx = 1.0f - wx, omy = 1.0f - wy;
            float w00 = omx * omy, w01 = omx * wy, w10 = wx * omy, w11 = wx * wy;
            f[2 * l]     = f00.x * w00 + f01.x * w01 + f10.x * w10 + f11.x * w11;
            f[2 * l + 1] = f00.y * w00 + f01.y * w01 + f10.y * w10 + f11.y * w11;
        }
        unsigned o = oidx[i];
        float4* ob = out + (size_t)o * 8u;
        #pragma unroll
        for (int c = 0; c < 8; ++c) {
            vfloat4 v = { f[4 * c], f[4 * c + 1], f[4 * c + 2], f[4 * c + 3] };
            __builtin_nontemporal_store(v, (vfloat4*)&ob[c]);
        }
    }
}

// ---------------- Fallback tier A: R5/R7 two-kernel (unsorted) -----------
__global__ __launch_bounds__(256, 8) void mre_big(
    const float* __restrict__ px, const float* __restrict__ py,
    const float2* __restrict__ hasht, vfloat2* __restrict__ ws,
    uint4 rm1v, unsigned N)
{
    unsigned bid = blockIdx.x;
    unsigned xcd = bid & 7u;
    unsigned lv  = xcd >> 1;
    unsigned bwl = (bid >> 3) * 2u + (xcd & 1u);
    int r = (int)(lv == 0u ? rm1v.x : lv == 1u ? rm1v.y
                                    : lv == 2u ? rm1v.z : rm1v.w);
    const char* hb = (const char*)hasht + ((size_t)(11u + lv) << 22);
    vfloat2* wbase = ws + (size_t)lv * N;
    float rf = (float)r;

    unsigned stride = 512u * 256u;
    #pragma unroll 2
    for (unsigned n = bwl * 256u + threadIdx.x; n < N; n += stride) {
        float x = px[n], y = py[n];
        float fx = x * rf, fy = y * rf;
        float x0f = floorf(fx), y0f = floorf(fy);
        float wx = fx - x0f, wy = fy - y0f;
        int ix0 = (int)x0f; ix0 = ix0 < 0 ? 0 : (ix0 > r ? r : ix0);
        int iy0 = (int)y0f; iy0 = iy0 < 0 ? 0 : (iy0 > r ? r : iy0);
        int ix1 = ix0 + 1 > r ? r : ix0 + 1;
        int iy1 = iy0 + 1 > r ? r : iy0 + 1;
        unsigned hy0 = (unsigned)iy0 * PRIME2;
        unsigned hy1 = (unsigned)iy1 * PRIME2;
        unsigned h00 = ((unsigned)ix0 ^ hy0) & TMASK;
        unsigned h10 = ((unsigned)ix1 ^ hy0) & TMASK;
        unsigned h01 = ((unsigned)ix0 ^ hy1) & TMASK;
        unsigned h11 = ((unsigned)ix1 ^ hy1) & TMASK;
        float2 f00, f01, f10, f11;
        pair_gather(hb, h00, h10, f00, f10);
        pair_gather(hb, h01, h11, f01, f11);
        float omx = 1.0f - wx, omy = 1.0f - wy;
        float w00 = omx * omy, w01 = omx * wy, w10 = wx * omy, w11 = wx * wy;
        vfloat2 acc;
        acc.x = f00.x * w00 + f01.x * w01 + f10.x * w10 + f11.x * w11;
        acc.y = f00.y * w00 + f01.y * w01 + f10.y * w10 + f11.y * w11;
        __builtin_nontemporal_store(acc, wbase + n);
    }
}

__global__ __launch_bounds__(256) void mre_rest(
    const float* __restrict__ cxp, const float* __restrict__ cyp,
    const float2* __restrict__ dense, const float2* __restrict__ hasht,
    const vfloat2* __restrict__ ws, float4* __restrict__ out,
    uint4 wa, uint4 wb, unsigned N)
{
    __shared__ float2 sdense[256];
    __shared__ __align__(16) float sout[64 * 36];
    sdense[threadIdx.x] = dense[threadIdx.x];
    __syncthreads();

    unsigned gid = blockIdx.x * 256u + threadIdx.x;
    unsigned n  = gid >> 2;
    unsigned j  = gid & 3u;
    unsigned nl = threadIdx.x >> 2;

    float x = cxp[n];
    float y = cyp[n];
    vfloat2 wsv = __builtin_nontemporal_load(&ws[(size_t)j * N + n]);

    unsigned W0 = wa.x, W1 = wa.y, W2 = wa.z, W3 = wa.w, W4 = wb.x, W5 = wb.y;
    unsigned u0 = j == 0u ? W0 : j == 1u ? W1 : j == 2u ? W3 : W4;
    unsigned u1 = j == 0u ? W0 : j == 1u ? W2 : j == 2u ? W3 : W5;
    unsigned u2 = j == 0u ? W1 : j == 1u ? W2 : j == 2u ? W4 : W5;
    unsigned s0 = (j & 1u) << 4;
    unsigned s1 = ((j + 1u) & 1u) << 4;
    int rm1[3] = { (int)((u0 >> s0) & 0xffffu),
                   (int)((u1 >> s1) & 0xffffu),
                   (int)((u2 >> s0) & 0xffffu) };

    unsigned h00[3], h01[3], h10[3], h11[3];
    unsigned tbo[3];
    float wx[3], wy[3];
    unsigned d00 = 0, d01 = 0, d10 = 0, d11 = 0;

    #pragma unroll
    for (int k = 0; k < 3; ++k) {
        int r = rm1[k];
        float rf = (float)r;
        float fx = x * rf, fy = y * rf;
        float x0f = floorf(fx), y0f = floorf(fy);
        wx[k] = fx - x0f;  wy[k] = fy - y0f;
        int ix0 = (int)x0f; ix0 = ix0 < 0 ? 0 : (ix0 > r ? r : ix0);
        int iy0 = (int)y0f; iy0 = iy0 < 0 ? 0 : (iy0 > r ? r : iy0);
        int ix1 = ix0 + 1 > r ? r : ix0 + 1;
        int iy1 = iy0 + 1 > r ? r : iy0 + 1;
        if (k == 0) { d00 = ix0 * 16 + iy0; d01 = ix0 * 16 + iy1;
                      d10 = ix1 * 16 + iy0; d11 = ix1 * 16 + iy1; }
        unsigned lvl = j * 3u + (unsigned)k;
        unsigned ti = lvl == 0u ? 0u : lvl - 1u;
        tbo[k] = ti << 22;
        unsigned hy0 = (unsigned)iy0 * PRIME2;
        unsigned hy1 = (unsigned)iy1 * PRIME2;
        h00[k] = ((unsigned)ix0 ^ hy0) & TMASK;
        h01[k] = ((unsigned)ix0 ^ hy1) & TMASK;
        h10[k] = ((unsigned)ix1 ^ hy0) & TMASK;
        h11[k] = ((unsigned)ix1 ^ hy1) & TMASK;
    }

    const char* hb = (const char*)hasht;
    float2 f00[3], f01[3], f10[3], f11[3];
    #pragma unroll
    for (int k = 1; k < 3; ++k) {
        const char* tp = hb + tbo[k];
        pair_gather(tp, h00[k], h10[k], f00[k], f10[k]);
        pair_gather(tp, h01[k], h11[k], f01[k], f11[k]);
    }
    if (j == 0u) {
        f00[0] = sdense[d00]; f01[0] = sdense[d01];
        f10[0] = sdense[d10]; f11[0] = sdense[d11];
    } else {
        const char* tp = hb + tbo[0];
        pair_gather(tp, h00[0], h10[0], f00[0], f10[0]);
        pair_gather(tp, h01[0], h11[0], f01[0], f11[0]);
    }

    float* so = &sout[nl * 36u];
    #pragma unroll
    for (int k = 0; k < 3; ++k) {
        float omx = 1.0f - wx[k], omy = 1.0f - wy[k];
        float w00 = omx * omy, w01 = omx * wy[k];
        float w10 = wx[k] * omy, w11 = wx[k] * wy[k];
        vfloat2 a;
        a.x = f00[k].x * w00 + f01[k].x * w01 + f10[k].x * w10 + f11[k].x * w11;
        a.y = f00[k].y * w00 + f01[k].y * w01 + f10[k].y * w10 + f11[k].y * w11;
        *(vfloat2*)&so[6u * j + 2u * (unsigned)k] = a;
    }
    *(vfloat2*)&so[24u + 2u * j] = wsv;

    __syncthreads();

    const vfloat4* sp = (const vfloat4*)&sout[nl * 36u + 8u * j];
    vfloat4 o0 = sp[0];
    vfloat4 o1 = sp[1];
    size_t base = (size_t)n * 8u + 2u * j;
    __builtin_nontemporal_store(o0, (vfloat4*)&out[base]);
    __builtin_nontemporal_store(o1, (vfloat4*)&out[base + 1]);
}

// ---------------- Fallback tier B: the proven R2 mono kernel -------------
__global__ __launch_bounds__(256) void mre_mono(
    const float* __restrict__ cxp, const float* __restrict__ cyp,
    const float2* __restrict__ dense, const float2* __restrict__ hasht,
    float4* __restrict__ out, uint4 wa, uint4 wb)
{
    __shared__ float2 sdense[256];
    sdense[threadIdx.x] = dense[threadIdx.x];
    __syncthreads();

    unsigned gid = blockIdx.x * 256u + threadIdx.x;
    unsigned n = gid >> 2;
    unsigned j = gid & 3u;

    float x = cxp[n];
    float y = cyp[n];

    unsigned w0 = j < 2u ? (j == 0u ? wa.x : wa.z) : (j == 2u ? wb.x : wb.z);
    unsigned w1 = j < 2u ? (j == 0u ? wa.y : wa.w) : (j == 2u ? wb.y : wb.w);
    int rm1[4] = { (int)(w0 & 0xffffu), (int)(w0 >> 16),
                   (int)(w1 & 0xffffu), (int)(w1 >> 16) };

    unsigned o00[4], o01[4], o10[4], o11[4];
    float wx[4], wy[4];
    unsigned d00 = 0, d01 = 0, d10 = 0, d11 = 0;
    const bool lvl0 = (j == 0u);

    #pragma unroll
    for (int k = 0; k < 4; ++k) {
        int r = rm1[k];
        float rf = (float)r;
        float fx = x * rf, fy = y * rf;
        float x0f = floorf(fx), y0f = floorf(fy);
        wx[k] = fx - x0f;  wy[k] = fy - y0f;
        int ix0 = (int)x0f; ix0 = ix0 < 0 ? 0 : (ix0 > r ? r : ix0);
        int iy0 = (int)y0f; iy0 = iy0 < 0 ? 0 : (iy0 > r ? r : iy0);
        int ix1 = ix0 + 1 > r ? r : ix0 + 1;
        int iy1 = iy0 + 1 > r ? r : iy0 + 1;
        if (k == 0) { d00 = ix0 * 16 + iy0; d01 = ix0 * 16 + iy1;
                      d10 = ix1 * 16 + iy0; d11 = ix1 * 16 + iy1; }
        unsigned ti = j * 4u + (unsigned)k;
        ti = ti == 0u ? 0u : ti - 1u;
        unsigned tb = ti << 22;
        unsigned hy0 = (unsigned)iy0 * PRIME2;
        unsigned hy1 = (unsigned)iy1 * PRIME2;
        o00[k] = tb + ((((unsigned)ix0 ^ hy0) & TMASK) << 3);
        o01[k] = tb + ((((unsigned)ix0 ^ hy1) & TMASK) << 3);
        o10[k] = tb + ((((unsigned)ix1 ^ hy0) & TMASK) << 3);
        o11[k] = tb + ((((unsigned)ix1 ^ hy1) & TMASK) << 3);
    }

    const char* hb = (const char*)hasht;
    float2 f00[4], f01[4], f10[4], f11[4];
    #pragma unroll
    for (int k = 1; k < 4; ++k) {
        f00[k] = *(const float2*)(hb + o00[k]);
        f01[k] = *(const float2*)(hb + o01[k]);
        f10[k] = *(const float2*)(hb + o10[k]);
        f11[k] = *(const float2*)(hb + o11[k]);
    }
    if (lvl0) {
        f00[0] = sdense[d00]; f01[0] = sdense[d01];
        f10[0] = sdense[d10]; f11[0] = sdense[d11];
    } else {
        f00[0] = *(const float2*)(hb + o00[0]);
        f01[0] = *(const float2*)(hb + o01[0]);
        f10[0] = *(const float2*)(hb + o10[0]);
        f11[0] = *(const float2*)(hb + o11[0]);
    }

    float2 acc[4];
    #pragma unroll
    for (int k = 0; k < 4; ++k) {
        float omx = 1.0f - wx[k], omy = 1.0f - wy[k];
        float w00 = omx * omy, w01 = omx * wy[k];
        float w10 = wx[k] * omy, w11 = wx[k] * wy[k];
        acc[k].x = f00[k].x * w00 + f01[k].x * w01 + f10[k].x * w10 + f11[k].x * w11;
        acc[k].y = f00[k].y * w00 + f01[k].y * w01 + f10[k].y * w10 + f11[k].y * w11;
    }

    vfloat4 o0 = { acc[0].x, acc[0].y, acc[1].x, acc[1].y };
    vfloat4 o1 = { acc[2].x, acc[2].y, acc[3].x, acc[3].y };
    size_t base = (size_t)n * 8u + 2u * j;
    __builtin_nontemporal_store(o0, (vfloat4*)&out[base]);
    __builtin_nontemporal_store(o1, (vfloat4*)&out[base + 1]);
}

extern "C" void kernel_launch(void* const* d_in, const int* in_sizes, int n_in,
                              void* d_out, int out_size, void* d_ws, size_t ws_size,
                              hipStream_t stream)
{
    const float*  cx    = (const float*)d_in[0];
    const float*  cy    = (const float*)d_in[1];
    const float2* dense = (const float2*)d_in[2];
    const float2* hasht = (const float2*)d_in[3];
    float4*       out   = (float4*)d_out;
    const unsigned N = (unsigned)in_sizes[0];

    // numpy RES_LEVELS replica (host glibc doubles — verified passing in R2)
    int r[16];
    for (int l = 0; l < 16; ++l) {
        double b = exp((log(2048.0) - log(16.0)) / 15.0);
        r[l] = (int)floor(16.0 * pow(b, (double)l));
    }
    unsigned pw[8];
    for (int k = 0; k < 8; ++k)
        pw[k] = (unsigned)(r[2 * k] - 1) | ((unsigned)(r[2 * k + 1] - 1) << 16);
    uint4 wa = make_uint4(pw[0], pw[1], pw[2], pw[3]);
    uint4 wb = make_uint4(pw[4], pw[5], pw[6], pw[7]);
    uint4 rm1v = make_uint4((unsigned)(r[12] - 1), (unsigned)(r[13] - 1),
                            (unsigned)(r[14] - 1), (unsigned)(r[15] - 1));

    long long total = (long long)N * 4;
    int blocks  = (int)((total + 255) / 256);
    int pblocks = (int)((N + 255u) / 256u);

    const unsigned NS = NBIN * CAP;                       // 3,145,728 slots
    size_t tbl_bytes    = (size_t)N * 32u;                // fallback ws[4][N]
    size_t sorted_bytes = (size_t)NS * 16u                // slot records
                        + (size_t)(NBIN + 1) * 4u         // cnt + ocnt
                        + (size_t)N * 12u;                // overflow x,y,idx

    if (ws_size >= sorted_bytes && d_ws != nullptr) {
        char* p = (char*)d_ws;
        vfloat4*  slots = (vfloat4*)p;      p += (size_t)NS * 16u;
        unsigned* cnt   = (unsigned*)p;     p += (size_t)(NBIN + 1) * 4u;
        float*    ox    = (float*)p;        p += (size_t)N * 4u;
        float*    oy    = (float*)p;        p += (size_t)N * 4u;
        unsigned* oix   = (unsigned*)p;

        hipLaunchKernelGGL(k_init,    dim3((NBIN + 256u) / 256u), dim3(256),
                           0, stream, cnt);
        hipLaunchKernelGGL(k_scatter, dim3(pblocks), dim3(256), 0, stream,
                           cx, cy, cnt, slots, ox, oy, oix, N);
        hipLaunchKernelGGL(mre_all,   dim3(NS / 64u), dim3(256), 0, stream,
                           slots, cnt, dense, hasht, out, wa, wb);
        hipLaunchKernelGGL(k_overflow, dim3(64), dim3(256), 0, stream,
                           ox, oy, oix, cnt, dense, hasht, out, wa, wb);
    } else if (ws_size >= tbl_bytes && d_ws != nullptr) {
        vfloat2* wst = (vfloat2*)d_ws;
        hipLaunchKernelGGL(mre_big, dim3(2048), dim3(256), 0, stream,
                           cx, cy, hasht, wst, rm1v, N);
        hipLaunchKernelGGL(mre_rest, dim3(blocks), dim3(256), 0, stream,
                           cx, cy, dense, hasht, (const vfloat2*)wst,
                           out, wa, wb, N);
    } else {
        hipLaunchKernelGGL(mre_mono, dim3(blocks), dim3(256), 0, stream,
                           cx, cy, dense, hasht, out, wa, wb);
    }
}

// Round 13
// 582.499 us; speedup vs baseline: 1.0297x; 1.0297x over previous
//
#include <hip/hip_runtime.h>
#include <math.h>
#include <stdint.h>

// MultiResEncoding: Instant-NGP 2D multires hash grid. N=2^21, 16 levels,
// F=2, table 2^19 x float2. Level 0 dense 16x16; levels 1..15 hashed.
//
// History: R5 level->XCD split. R7 x-pair merge (PRIME[0]==1: even-ix
//   corners = one 16-B pair). R8: nt LOADS = L2 no-allocate on gfx950 --
//   never nt-load data you want cached. R11/R12: spatial binning -> sorted
//   gathers 272->178 us (gather cost ~ unique lines/wave, CONFIRMED).
// R13: FUSED sorted kernel (wave j = levels 4j..4j+3): sliding hash window
//   keeps saturated levels L2-resident (FETCH 101 MB). BEST: 588.7.
// R14: FAILED (+11 us): validity-from-count (no sentinel init) -- the
//   sentinel init doubled as slot-region warm/prefetch; cnt-broadcast +
//   selects + cold unwritten-slot reads cost more than the 8-us fill saved.
// R15 (this round): R13 exactly; ONE variable: bin grid 128^2 -> 114^2
//   (mu 128 -> 161, CAP still 192 = 3x64 blocks). NS 3.15M -> 2.50M slots
//   (-21%): slot traffic 50->40 MB, blocks 49152->38988. Overflow risk at
//   mu=161: z=2.5 -> ~100-400 pts -> exact k_overflow path (correct for
//   any input). Wave line-sharing degrades marginally (L15 ~30->50 lines).

#define TMASK  ((1u << 19) - 1)
#define PRIME2 2654435761u
#define GRIDW  114u            // 114 x 114 spatial bins
#define NBIN   (GRIDW * GRIDW) // 12996
#define CAP    192u            // slots per bin = 3 blocks of 64
#define INVOG  0xFFFFFFFFu

typedef float vfloat4 __attribute__((ext_vector_type(4)));
typedef float vfloat2 __attribute__((ext_vector_type(2)));

// Divergent merged gather (R7, proven): if h1 in {h0, h0^1} (even-ix0 pair
// or clamped edge), one 16-B load covers both entries; else two 8-B loads.
__device__ __forceinline__ void pair_gather(const char* tp, unsigned h0,
                                            unsigned h1, float2& a, float2& b)
{
    if (((h0 ^ h1) | 1u) == 1u) {
        vfloat4 q = *(const vfloat4*)(tp + ((h0 & ~1u) << 3));
        a.x = (h0 & 1u) ? q.z : q.x;  a.y = (h0 & 1u) ? q.w : q.y;
        b.x = (h1 & 1u) ? q.z : q.x;  b.y = (h1 & 1u) ? q.w : q.y;
    } else {
        a = *(const float2*)(tp + ((size_t)h0 << 3));
        b = *(const float2*)(tp + ((size_t)h1 << 3));
    }
}

__device__ __forceinline__ unsigned bin_of(float x, float y)
{
    int bx = (int)(x * (float)GRIDW);
    bx = bx < 0 ? 0 : (bx > (int)GRIDW - 1 ? (int)GRIDW - 1 : bx);
    int by = (int)(y * (float)GRIDW);
    by = by < 0 ? 0 : (by > (int)GRIDW - 1 ? (int)GRIDW - 1 : by);
    return (unsigned)by * GRIDW + (unsigned)bx;
}

// ---------------- init: sentinel records + counters ----------------------
__global__ void k_init(vfloat4* __restrict__ slots, unsigned* __restrict__ cnt,
                       unsigned NS)
{
    unsigned i = blockIdx.x * 256u + threadIdx.x;
    if (i < NS) { vfloat4 s = { -1.0f, -1.0f, 0.0f, 0.0f }; slots[i] = s; }
    if (i <= NBIN) cnt[i] = 0u;                    // bins + ocnt at [NBIN]
}

// ---------------- scatter: one atomic + ONE 16-B store per point ---------
__global__ void k_scatter(const float* __restrict__ cx, const float* __restrict__ cy,
                          unsigned* __restrict__ cnt, vfloat4* __restrict__ slots,
                          float* __restrict__ ox, float* __restrict__ oy,
                          unsigned* __restrict__ oidx, unsigned N)
{
    unsigned i = blockIdx.x * 256u + threadIdx.x;
    if (i >= N) return;
    float x = cx[i], y = cy[i];
    unsigned b = bin_of(x, y);
    unsigned pos = atomicAdd(&cnt[b], 1u);
    if (pos < CAP) {
        vfloat4 rec = { x, y, __uint_as_float(i), 0.0f };
        slots[b * CAP + pos] = rec;
    } else {                                       // ~100-400 pts at mu=161
        unsigned op = atomicAdd(&cnt[NBIN], 1u);   // capacity N: always fits
        ox[op] = x; oy[op] = y; oidx[op] = i;
    }
}

// ---------------- fused main kernel: all 16 levels, sorted ---------------
// 64 sorted slots/block; wave j handles levels {4j..4j+3} for all 64 pts.
__global__ __launch_bounds__(256) void mre_all(
    const vfloat4* __restrict__ slots,
    const float2* __restrict__ dense, const float2* __restrict__ hasht,
    float4* __restrict__ out, uint4 wa, uint4 wb)
{
    __shared__ float2 sdense[256];                 // 16x16 level-0 grid, 2 KB
    __shared__ __align__(16) float sout[64 * 36];  // 64 pts x 32 feats, +4 pad
    __shared__ unsigned sorig[64];
    sdense[threadIdx.x] = dense[threadIdx.x];

    unsigned j  = threadIdx.x >> 6;                // wave = level group
    unsigned nl = threadIdx.x & 63u;               // slot within block
    unsigned slot = blockIdx.x * 64u + nl;         // block never straddles bin
    vfloat4 rec = slots[slot];                     // coalesced 16 B
    float x = rec.x, y = rec.y;                    // -1 sentinel if empty
    bool valid = (x >= 0.0f);
    if (j == 0u) sorig[nl] = valid ? __float_as_uint(rec.z) : INVOG;
    __syncthreads();

    if (__ballot(valid) != 0ull) {
        // levels 4j..4j+3 live in words 2j, 2j+1 (wave-uniform selects)
        unsigned w0 = j == 0u ? wa.x : j == 1u ? wa.z : j == 2u ? wb.x : wb.z;
        unsigned w1 = j == 0u ? wa.y : j == 1u ? wa.w : j == 2u ? wb.y : wb.w;
        int rm1[4] = { (int)(w0 & 0xffffu), (int)(w0 >> 16),
                       (int)(w1 & 0xffffu), (int)(w1 >> 16) };

        unsigned h00[4], h01[4], h10[4], h11[4];
        unsigned tbo[4];
        float wx[4], wy[4];
        unsigned d00 = 0, d01 = 0, d10 = 0, d11 = 0;

        #pragma unroll
        for (int k = 0; k < 4; ++k) {
            int r = rm1[k];
            float rf = (float)r;
            float fx = x * rf, fy = y * rf;
            float x0f = floorf(fx), y0f = floorf(fy);
            wx[k] = fx - x0f;  wy[k] = fy - y0f;
            int ix0 = (int)x0f; ix0 = ix0 < 0 ? 0 : (ix0 > r ? r : ix0);
            int iy0 = (int)y0f; iy0 = iy0 < 0 ? 0 : (iy0 > r ? r : iy0);
            int ix1 = ix0 + 1 > r ? r : ix0 + 1;
            int iy1 = iy0 + 1 > r ? r : iy0 + 1;
            if (k == 0) { d00 = ix0 * 16 + iy0; d01 = ix0 * 16 + iy1;
                          d10 = ix1 * 16 + iy0; d11 = ix1 * 16 + iy1; }
            unsigned lvl = j * 4u + (unsigned)k;   // level of this slot
            unsigned ti = lvl == 0u ? 0u : lvl - 1u;
            tbo[k] = ti << 22;                     // ti * 2^19 * 8 B
            unsigned hy0 = (unsigned)iy0 * PRIME2;
            unsigned hy1 = (unsigned)iy1 * PRIME2;
            h00[k] = ((unsigned)ix0 ^ hy0) & TMASK;
            h01[k] = ((unsigned)ix0 ^ hy1) & TMASK;
            h10[k] = ((unsigned)ix1 ^ hy0) & TMASK;
            h11[k] = ((unsigned)ix1 ^ hy1) & TMASK;
        }

        const char* hb = (const char*)hasht;
        float2 f00[4], f01[4], f10[4], f11[4];
        #pragma unroll
        for (int k = 1; k < 4; ++k) {              // unconditional: issue first
            const char* tp = hb + tbo[k];
            pair_gather(tp, h00[k], h10[k], f00[k], f10[k]);
            pair_gather(tp, h01[k], h11[k], f01[k], f11[k]);
        }
        if (j == 0u) {                             // whole wave 0: LDS dense
            f00[0] = sdense[d00]; f01[0] = sdense[d01];
            f10[0] = sdense[d10]; f11[0] = sdense[d11];
        } else {
            const char* tp = hb + tbo[0];
            pair_gather(tp, h00[0], h10[0], f00[0], f10[0]);
            pair_gather(tp, h01[0], h11[0], f01[0], f11[0]);
        }

        // bilerp -> contiguous quadrant floats [8j..8j+7] of this point's row
        float* so = &sout[nl * 36u + 8u * j];
        #pragma unroll
        for (int k = 0; k < 4; ++k) {
            float omx = 1.0f - wx[k], omy = 1.0f - wy[k];
            float w00 = omx * omy, w01 = omx * wy[k];
            float w10 = wx[k] * omy, w11 = wx[k] * wy[k];
            vfloat2 a;
            a.x = f00[k].x * w00 + f01[k].x * w01 + f10[k].x * w10 + f11[k].x * w11;
            a.y = f00[k].y * w00 + f01[k].y * w01 + f10[k].y * w10 + f11[k].y * w11;
            *(vfloat2*)&so[2u * (unsigned)k] = a;
        }
    }
    __syncthreads();

    // store: 8 lanes per point -> full 128-B line at out[orig], two passes
    unsigned c  = threadIdx.x & 7u;
    unsigned q0 = threadIdx.x >> 3;                // 0..31
    #pragma unroll
    for (int p = 0; p < 2; ++p) {
        unsigned q = q0 + 32u * p;
        unsigned oo = sorig[q];
        if (oo != INVOG) {
            vfloat4 v = *(const vfloat4*)&sout[q * 36u + c * 4u];
            __builtin_nontemporal_store(v, (vfloat4*)(out + (size_t)oo * 8u + c));
        }
    }
}

// ---------------- overflow: all 16 levels direct (exact same FP ops) -----
__global__ void k_overflow(const float* __restrict__ ox, const float* __restrict__ oy,
                           const unsigned* __restrict__ oidx,
                           const unsigned* __restrict__ cnt,
                           const float2* __restrict__ dense,
                           const float2* __restrict__ hasht,
                           float4* __restrict__ out, uint4 wa, uint4 wb)
{
    unsigned ocnt = cnt[NBIN];
    unsigned pwv[8] = { wa.x, wa.y, wa.z, wa.w, wb.x, wb.y, wb.z, wb.w };
    const char* hb = (const char*)hasht;
    for (unsigned i = blockIdx.x * 256u + threadIdx.x; i < ocnt;
         i += gridDim.x * 256u) {
        float x = ox[i], y = oy[i];
        float f[32];
        #pragma unroll
        for (int l = 0; l < 16; ++l) {
            int r = (int)((pwv[l >> 1] >> ((l & 1) << 4)) & 0xffffu);
            float rf = (float)r;
            float fx = x * rf, fy = y * rf;
            float x0f = floorf(fx), y0f = floorf(fy);
            float wx = fx - x0f, wy = fy - y0f;
            int ix0 = (int)x0f; ix0 = ix0 < 0 ? 0 : (ix0 > r ? r : ix0);
            int iy0 = (int)y0f; iy0 = iy0 < 0 ? 0 : (iy0 > r ? r : iy0);
            int ix1 = ix0 + 1 > r ? r : ix0 + 1;
            int iy1 = iy0 + 1 > r ? r : iy0 + 1;
            float2 f00, f01, f10, f11;
            if (l == 0) {
                f00 = dense[ix0 * 16 + iy0]; f01 = dense[ix0 * 16 + iy1];
                f10 = dense[ix1 * 16 + iy0]; f11 = dense[ix1 * 16 + iy1];
            } else {
                const char* tp = hb + ((size_t)(l - 1) << 22);
                unsigned hy0 = (unsigned)iy0 * PRIME2;
                unsigned hy1 = (unsigned)iy1 * PRIME2;
                f00 = *(const float2*)(tp + ((size_t)(((unsigned)ix0 ^ hy0) & TMASK) << 3));
                f01 = *(const float2*)(tp + ((size_t)(((unsigned)ix0 ^ hy1) & TMASK) << 3));
                f10 = *(const float2*)(tp + ((size_t)(((unsigned)ix1 ^ hy0) & TMASK) << 3));
                f11 = *(const float2*)(tp + ((size_t)(((unsigned)ix1 ^ hy1) & TMASK) << 3));
            }
            float omx = 1.0f - wx, omy = 1.0f - wy;
            float w00 = omx * omy, w01 = omx * wy, w10 = wx * omy, w11 = wx * wy;
            f[2 * l]     = f00.x * w00 + f01.x * w01 + f10.x * w10 + f11.x * w11;
            f[2 * l + 1] = f00.y * w00 + f01.y * w01 + f10.y * w10 + f11.y * w11;
        }
        unsigned o = oidx[i];
        float4* ob = out + (size_t)o * 8u;
        #pragma unroll
        for (int c = 0; c < 8; ++c) {
            vfloat4 v = { f[4 * c], f[4 * c + 1], f[4 * c + 2], f[4 * c + 3] };
            __builtin_nontemporal_store(v, (vfloat4*)&ob[c]);
        }
    }
}

// ---------------- Fallback tier A: R5/R7 two-kernel (unsorted) -----------
__global__ __launch_bounds__(256, 8) void mre_big(
    const float* __restrict__ px, const float* __restrict__ py,
    const float2* __restrict__ hasht, vfloat2* __restrict__ ws,
    uint4 rm1v, unsigned N)
{
    unsigned bid = blockIdx.x;
    unsigned xcd = bid & 7u;
    unsigned lv  = xcd >> 1;
    unsigned bwl = (bid >> 3) * 2u + (xcd & 1u);
    int r = (int)(lv == 0u ? rm1v.x : lv == 1u ? rm1v.y
                                    : lv == 2u ? rm1v.z : rm1v.w);
    const char* hb = (const char*)hasht + ((size_t)(11u + lv) << 22);
    vfloat2* wbase = ws + (size_t)lv * N;
    float rf = (float)r;

    unsigned stride = 512u * 256u;
    #pragma unroll 2
    for (unsigned n = bwl * 256u + threadIdx.x; n < N; n += stride) {
        float x = px[n], y = py[n];
        float fx = x * rf, fy = y * rf;
        float x0f = floorf(fx), y0f = floorf(fy);
        float wx = fx - x0f, wy = fy - y0f;
        int ix0 = (int)x0f; ix0 = ix0 < 0 ? 0 : (ix0 > r ? r : ix0);
        int iy0 = (int)y0f; iy0 = iy0 < 0 ? 0 : (iy0 > r ? r : iy0);
        int ix1 = ix0 + 1 > r ? r : ix0 + 1;
        int iy1 = iy0 + 1 > r ? r : iy0 + 1;
        unsigned hy0 = (unsigned)iy0 * PRIME2;
        unsigned hy1 = (unsigned)iy1 * PRIME2;
        unsigned h00 = ((unsigned)ix0 ^ hy0) & TMASK;
        unsigned h10 = ((unsigned)ix1 ^ hy0) & TMASK;
        unsigned h01 = ((unsigned)ix0 ^ hy1) & TMASK;
        unsigned h11 = ((unsigned)ix1 ^ hy1) & TMASK;
        float2 f00, f01, f10, f11;
        pair_gather(hb, h00, h10, f00, f10);
        pair_gather(hb, h01, h11, f01, f11);
        float omx = 1.0f - wx, omy = 1.0f - wy;
        float w00 = omx * omy, w01 = omx * wy, w10 = wx * omy, w11 = wx * wy;
        vfloat2 acc;
        acc.x = f00.x * w00 + f01.x * w01 + f10.x * w10 + f11.x * w11;
        acc.y = f00.y * w00 + f01.y * w01 + f10.y * w10 + f11.y * w11;
        __builtin_nontemporal_store(acc, wbase + n);
    }
}

__global__ __launch_bounds__(256) void mre_rest(
    const float* __restrict__ cxp, const float* __restrict__ cyp,
    const float2* __restrict__ dense, const float2* __restrict__ hasht,
    const vfloat2* __restrict__ ws, float4* __restrict__ out,
    uint4 wa, uint4 wb, unsigned N)
{
    __shared__ float2 sdense[256];
    __shared__ __align__(16) float sout[64 * 36];
    sdense[threadIdx.x] = dense[threadIdx.x];
    __syncthreads();

    unsigned gid = blockIdx.x * 256u + threadIdx.x;
    unsigned n  = gid >> 2;
    unsigned j  = gid & 3u;
    unsigned nl = threadIdx.x >> 2;

    float x = cxp[n];
    float y = cyp[n];
    vfloat2 wsv = __builtin_nontemporal_load(&ws[(size_t)j * N + n]);

    unsigned W0 = wa.x, W1 = wa.y, W2 = wa.z, W3 = wa.w, W4 = wb.x, W5 = wb.y;
    unsigned u0 = j == 0u ? W0 : j == 1u ? W1 : j == 2u ? W3 : W4;
    unsigned u1 = j == 0u ? W0 : j == 1u ? W2 : j == 2u ? W3 : W5;
    unsigned u2 = j == 0u ? W1 : j == 1u ? W2 : j == 2u ? W4 : W5;
    unsigned s0 = (j & 1u) << 4;
    unsigned s1 = ((j + 1u) & 1u) << 4;
    int rm1[3] = { (int)((u0 >> s0) & 0xffffu),
                   (int)((u1 >> s1) & 0xffffu),
                   (int)((u2 >> s0) & 0xffffu) };

    unsigned h00[3], h01[3], h10[3], h11[3];
    unsigned tbo[3];
    float wx[3], wy[3];
    unsigned d00 = 0, d01 = 0, d10 = 0, d11 = 0;

    #pragma unroll
    for (int k = 0; k < 3; ++k) {
        int r = rm1[k];
        float rf = (float)r;
        float fx = x * rf, fy = y * rf;
        float x0f = floorf(fx), y0f = floorf(fy);
        wx[k] = fx - x0f;  wy[k] = fy - y0f;
        int ix0 = (int)x0f; ix0 = ix0 < 0 ? 0 : (ix0 > r ? r : ix0);
        int iy0 = (int)y0f; iy0 = iy0 < 0 ? 0 : (iy0 > r ? r : iy0);
        int ix1 = ix0 + 1 > r ? r : ix0 + 1;
        int iy1 = iy0 + 1 > r ? r : iy0 + 1;
        if (k == 0) { d00 = ix0 * 16 + iy0; d01 = ix0 * 16 + iy1;
                      d10 = ix1 * 16 + iy0; d11 = ix1 * 16 + iy1; }
        unsigned lvl = j * 3u + (unsigned)k;
        unsigned ti = lvl == 0u ? 0u : lvl - 1u;
        tbo[k] = ti << 22;
        unsigned hy0 = (unsigned)iy0 * PRIME2;
        unsigned hy1 = (unsigned)iy1 * PRIME2;
        h00[k] = ((unsigned)ix0 ^ hy0) & TMASK;
        h01[k] = ((unsigned)ix0 ^ hy1) & TMASK;
        h10[k] = ((unsigned)ix1 ^ hy0) & TMASK;
        h11[k] = ((unsigned)ix1 ^ hy1) & TMASK;
    }

    const char* hb = (const char*)hasht;
    float2 f00[3], f01[3], f10[3], f11[3];
    #pragma unroll
    for (int k = 1; k < 3; ++k) {
        const char* tp = hb + tbo[k];
        pair_gather(tp, h00[k], h10[k], f00[k], f10[k]);
        pair_gather(tp, h01[k], h11[k], f01[k], f11[k]);
    }
    if (j == 0u) {
        f00[0] = sdense[d00]; f01[0] = sdense[d01];
        f10[0] = sdense[d10]; f11[0] = sdense[d11];
    } else {
        const char* tp = hb + tbo[0];
        pair_gather(tp, h00[0], h10[0], f00[0], f10[0]);
        pair_gather(tp, h01[0], h11[0], f01[0], f11[0]);
    }

    float* so = &sout[nl * 36u];
    #pragma unroll
    for (int k = 0; k < 3; ++k) {
        float omx = 1.0f - wx[k], omy = 1.0f - wy[k];
        float w00 = omx * omy, w01 = omx * wy[k];
        float w10 = wx[k] * omy, w11 = wx[k] * wy[k];
        vfloat2 a;
        a.x = f00[k].x * w00 + f01[k].x * w01 + f10[k].x * w10 + f11[k].x * w11;
        a.y = f00[k].y * w00 + f01[k].y * w01 + f10[k].y * w10 + f11[k].y * w11;
        *(vfloat2*)&so[6u * j + 2u * (unsigned)k] = a;
    }
    *(vfloat2*)&so[24u + 2u * j] = wsv;

    __syncthreads();

    const vfloat4* sp = (const vfloat4*)&sout[nl * 36u + 8u * j];
    vfloat4 o0 = sp[0];
    vfloat4 o1 = sp[1];
    size_t base = (size_t)n * 8u + 2u * j;
    __builtin_nontemporal_store(o0, (vfloat4*)&out[base]);
    __builtin_nontemporal_store(o1, (vfloat4*)&out[base + 1]);
}

// ---------------- Fallback tier B: the proven R2 mono kernel -------------
__global__ __launch_bounds__(256) void mre_mono(
    const float* __restrict__ cxp, const float* __restrict__ cyp,
    const float2* __restrict__ dense, const float2* __restrict__ hasht,
    float4* __restrict__ out, uint4 wa, uint4 wb)
{
    __shared__ float2 sdense[256];
    sdense[threadIdx.x] = dense[threadIdx.x];
    __syncthreads();

    unsigned gid = blockIdx.x * 256u + threadIdx.x;
    unsigned n = gid >> 2;
    unsigned j = gid & 3u;

    float x = cxp[n];
    float y = cyp[n];

    unsigned w0 = j < 2u ? (j == 0u ? wa.x : wa.z) : (j == 2u ? wb.x : wb.z);
    unsigned w1 = j < 2u ? (j == 0u ? wa.y : wa.w) : (j == 2u ? wb.y : wb.w);
    int rm1[4] = { (int)(w0 & 0xffffu), (int)(w0 >> 16),
                   (int)(w1 & 0xffffu), (int)(w1 >> 16) };

    unsigned o00[4], o01[4], o10[4], o11[4];
    float wx[4], wy[4];
    unsigned d00 = 0, d01 = 0, d10 = 0, d11 = 0;
    const bool lvl0 = (j == 0u);

    #pragma unroll
    for (int k = 0; k < 4; ++k) {
        int r = rm1[k];
        float rf = (float)r;
        float fx = x * rf, fy = y * rf;
        float x0f = floorf(fx), y0f = floorf(fy);
        wx[k] = fx - x0f;  wy[k] = fy - y0f;
        int ix0 = (int)x0f; ix0 = ix0 < 0 ? 0 : (ix0 > r ? r : ix0);
        int iy0 = (int)y0f; iy0 = iy0 < 0 ? 0 : (iy0 > r ? r : iy0);
        int ix1 = ix0 + 1 > r ? r : ix0 + 1;
        int iy1 = iy0 + 1 > r ? r : iy0 + 1;
        if (k == 0) { d00 = ix0 * 16 + iy0; d01 = ix0 * 16 + iy1;
                      d10 = ix1 * 16 + iy0; d11 = ix1 * 16 + iy1; }
        unsigned ti = j * 4u + (unsigned)k;
        ti = ti == 0u ? 0u : ti - 1u;
        unsigned tb = ti << 22;
        unsigned hy0 = (unsigned)iy0 * PRIME2;
        unsigned hy1 = (unsigned)iy1 * PRIME2;
        o00[k] = tb + ((((unsigned)ix0 ^ hy0) & TMASK) << 3);
        o01[k] = tb + ((((unsigned)ix0 ^ hy1) & TMASK) << 3);
        o10[k] = tb + ((((unsigned)ix1 ^ hy0) & TMASK) << 3);
        o11[k] = tb + ((((unsigned)ix1 ^ hy1) & TMASK) << 3);
    }

    const char* hb = (const char*)hasht;
    float2 f00[4], f01[4], f10[4], f11[4];
    #pragma unroll
    for (int k = 1; k < 4; ++k) {
        f00[k] = *(const float2*)(hb + o00[k]);
        f01[k] = *(const float2*)(hb + o01[k]);
        f10[k] = *(const float2*)(hb + o10[k]);
        f11[k] = *(const float2*)(hb + o11[k]);
    }
    if (lvl0) {
        f00[0] = sdense[d00]; f01[0] = sdense[d01];
        f10[0] = sdense[d10]; f11[0] = sdense[d11];
    } else {
        f00[0] = *(const float2*)(hb + o00[0]);
        f01[0] = *(const float2*)(hb + o01[0]);
        f10[0] = *(const float2*)(hb + o10[0]);
        f11[0] = *(const float2*)(hb + o11[0]);
    }

    float2 acc[4];
    #pragma unroll
    for (int k = 0; k < 4; ++k) {
        float omx = 1.0f - wx[k], omy = 1.0f - wy[k];
        float w00 = omx * omy, w01 = omx * wy[k];
        float w10 = wx[k] * omy, w11 = wx[k] * wy[k];
        acc[k].x = f00[k].x * w00 + f01[k].x * w01 + f10[k].x * w10 + f11[k].x * w11;
        acc[k].y = f00[k].y * w00 + f01[k].y * w01 + f10[k].y * w10 + f11[k].y * w11;
    }

    vfloat4 o0 = { acc[0].x, acc[0].y, acc[1].x, acc[1].y };
    vfloat4 o1 = { acc[2].x, acc[2].y, acc[3].x, acc[3].y };
    size_t base = (size_t)n * 8u + 2u * j;
    __builtin_nontemporal_store(o0, (vfloat4*)&out[base]);
    __builtin_nontemporal_store(o1, (vfloat4*)&out[base + 1]);
}

extern "C" void kernel_launch(void* const* d_in, const int* in_sizes, int n_in,
                              void* d_out, int out_size, void* d_ws, size_t ws_size,
                              hipStream_t stream)
{
    const float*  cx    = (const float*)d_in[0];
    const float*  cy    = (const float*)d_in[1];
    const float2* dense = (const float2*)d_in[2];
    const float2* hasht = (const float2*)d_in[3];
    float4*       out   = (float4*)d_out;
    const unsigned N = (unsigned)in_sizes[0];

    // numpy RES_LEVELS replica (host glibc doubles — verified passing in R2)
    int r[16];
    for (int l = 0; l < 16; ++l) {
        double b = exp((log(2048.0) - log(16.0)) / 15.0);
        r[l] = (int)floor(16.0 * pow(b, (double)l));
    }
    unsigned pw[8];
    for (int k = 0; k < 8; ++k)
        pw[k] = (unsigned)(r[2 * k] - 1) | ((unsigned)(r[2 * k + 1] - 1) << 16);
    uint4 wa = make_uint4(pw[0], pw[1], pw[2], pw[3]);
    uint4 wb = make_uint4(pw[4], pw[5], pw[6], pw[7]);
    uint4 rm1v = make_uint4((unsigned)(r[12] - 1), (unsigned)(r[13] - 1),
                            (unsigned)(r[14] - 1), (unsigned)(r[15] - 1));

    long long total = (long long)N * 4;
    int blocks  = (int)((total + 255) / 256);
    int pblocks = (int)((N + 255u) / 256u);

    const unsigned NS = NBIN * CAP;                       // 2,495,232 slots
    size_t tbl_bytes    = (size_t)N * 32u;                // fallback ws[4][N]
    size_t sorted_bytes = (size_t)NS * 16u                // slot records
                        + (size_t)(NBIN + 1) * 4u         // cnt + ocnt
                        + (size_t)N * 12u;                // overflow x,y,idx

    if (ws_size >= sorted_bytes && d_ws != nullptr) {
        char* p = (char*)d_ws;
        vfloat4*  slots = (vfloat4*)p;      p += (size_t)NS * 16u;
        unsigned* cnt   = (unsigned*)p;     p += (size_t)(NBIN + 1) * 4u;
        float*    ox    = (float*)p;        p += (size_t)N * 4u;
        float*    oy    = (float*)p;        p += (size_t)N * 4u;
        unsigned* oix   = (unsigned*)p;

        int iblocks = (int)((NS + 255u) / 256u);
        hipLaunchKernelGGL(k_init,    dim3(iblocks), dim3(256), 0, stream,
                           slots, cnt, NS);
        hipLaunchKernelGGL(k_scatter, dim3(pblocks), dim3(256), 0, stream,
                           cx, cy, cnt, slots, ox, oy, oix, N);
        hipLaunchKernelGGL(mre_all,   dim3(NS / 64u), dim3(256), 0, stream,
                           slots, dense, hasht, out, wa, wb);
        hipLaunchKernelGGL(k_overflow, dim3(64), dim3(256), 0, stream,
                           ox, oy, oix, cnt, dense, hasht, out, wa, wb);
    } else if (ws_size >= tbl_bytes && d_ws != nullptr) {
        vfloat2* wst = (vfloat2*)d_ws;
        hipLaunchKernelGGL(mre_big, dim3(2048), dim3(256), 0, stream,
                           cx, cy, hasht, wst, rm1v, N);
        hipLaunchKernelGGL(mre_rest, dim3(blocks), dim3(256), 0, stream,
                           cx, cy, dense, hasht, (const vfloat2*)wst,
                           out, wa, wb, N);
    } else {
        hipLaunchKernelGGL(mre_mono, dim3(blocks), dim3(256), 0, stream,
                           cx, cy, dense, hasht, out, wa, wb);
    }
}